// Round 7
// baseline (887.631 us; speedup 1.0000x reference)
//
#include <hip/hip_runtime.h>
#include <hip/hip_fp16.h>
#include <cstdint>

#define HC 168    // H*C (logical)
#define CC 42     // C per head
#define NH 4      // heads
#define PH 44     // padded channels per head
#define HP 176    // padded halves per h16 row (= 4*44), pitch of h16
#define HPB 352   // bytes per h16 row
#define AP 192    // actv row pitch (halves), zero-padded K for KCN=6
#define A0P 64    // act0/x16 row pitch (halves), KCN=2
#define NEG 0.2f

typedef _Float16 f16;
typedef __attribute__((ext_vector_type(8))) _Float16 f16x8;
typedef __attribute__((ext_vector_type(4))) float f32x4;

__device__ __forceinline__ float lrelu(float v) { return fmaxf(v, NEG * v); }
__device__ __forceinline__ float eluf(float v)  { return v > 0.f ? v : __expf(v) - 1.f; }

__device__ __forceinline__ float sel4(float4 w, int h) {
  float r = w.x;
  r = (h == 1) ? w.y : r;
  r = (h == 2) ? w.z : r;
  r = (h == 3) ? w.w : r;
  return r;
}

// ---------------- cast x (fp32, [N][42]) -> x16 ([N][64] fp16, zero pad) ----
__global__ void cast16_kernel(const float* __restrict__ X, f16* __restrict__ O, int N) {
  int i = blockIdx.x * 256 + threadIdx.x;
  if (i >= N * A0P) return;
  int n = i >> 6, c = i & 63;
  O[i] = (c < CC) ? (f16)X[n * CC + c] : (f16)0.f;
}

// ---------------- W -> fragment-layout fp16 table ----------------
// Wf[((ct*KCN+kc)*64+lane)*8+j]; k-slot: kp = kc*32+(lane>>4)*8+j, col: cl = ct*16+(lane&15).
// kpad/cpad: map padded-head index (h*44+c, c<42 valid) back to original.
__global__ void wconv_kernel(const float* __restrict__ W, f16* __restrict__ Wf,
                             int NCT, int KCN, int kpad, int Fink, int cpad, int Ncols,
                             int wstride) {
  int i = blockIdx.x * 256 + threadIdx.x;
  int tot = NCT * KCN * 64;
  if (i >= tot) return;
  int lane = i & 63;
  int t = i >> 6;
  int kc = t % KCN;
  int ct = t / KCN;
  int cl = ct * 16 + (lane & 15);
  int corig; bool cok;
  if (cpad) { int h = cl / PH, c = cl % PH; cok = (c < CC && h < NH); corig = h * CC + c; }
  else      { cok = (cl < Ncols); corig = cl; }
  f16 vals[8];
#pragma unroll
  for (int j = 0; j < 8; ++j) {
    int kp = kc * 32 + (lane >> 4) * 8 + j;
    int korig; bool kok;
    if (kpad) { int h = kp / PH, c = kp % PH; kok = (c < CC && h < NH && kp < HP); korig = h * CC + c; }
    else      { kok = (kp < Fink); korig = kp; }
    vals[j] = (kok && cok) ? (f16)W[korig * wstride + corig] : (f16)0.f;
  }
  *(f16x8*)(Wf + (size_t)i * 8) = *(f16x8*)vals;
}

// ---------------- lin0 MFMA: act0[N,64] = elu(x16 @ Wf0 + b) ----------------
__global__ __launch_bounds__(256) void mfma_gemm0_kernel(
    const f16* __restrict__ A, const f16* __restrict__ Wf,
    const float* __restrict__ bias, f16* __restrict__ Out, int N) {
  const int lane = threadIdx.x & 63;
  const int wid = (blockIdx.x * 256 + threadIdx.x) >> 6;
  const int row0 = wid * 16;
  if (row0 >= N) return;
  const int r = lane & 15, g = lane >> 4;
  f16x8 a[2];
  const f16* ap = A + (int64_t)(row0 + r) * A0P + g * 8;
#pragma unroll
  for (int kc = 0; kc < 2; ++kc) a[kc] = *(const f16x8*)(ap + kc * 32);
  f16* op = Out + (int64_t)row0 * A0P;
#pragma unroll
  for (int ct = 0; ct < 4; ++ct) {
    f32x4 acc = {0.f, 0.f, 0.f, 0.f};
#pragma unroll
    for (int kc = 0; kc < 2; ++kc) {
      f16x8 b = *(const f16x8*)(Wf + (((size_t)ct * 2 + kc) * 64 + lane) * 8);
      acc = __builtin_amdgcn_mfma_f32_16x16x32_f16(a[kc], b, acc, 0, 0, 0);
    }
    const int col = ct * 16 + r;
    float bv = (col < CC) ? bias[col] : 0.f;
#pragma unroll
    for (int v = 0; v < 4; ++v) {
      f16 o = (col < CC) ? (f16)eluf(acc[v] + bv) : (f16)0.f;
      op[(int64_t)(g * 4 + v) * A0P + col] = o;
    }
  }
}

// ---------------- layer MFMA: h16[N,176pad] = act @ Wf ----------------
template<int KCN>
__global__ __launch_bounds__(256) void mfma_gemmL_kernel(
    const f16* __restrict__ A, const f16* __restrict__ Wf,
    f16* __restrict__ Out, int N) {
  const int lane = threadIdx.x & 63;
  const int wid = (blockIdx.x * 256 + threadIdx.x) >> 6;
  const int row0 = wid * 16;
  if (row0 >= N) return;
  const int r = lane & 15, g = lane >> 4;
  f16x8 a[KCN];
  const f16* ap = A + (int64_t)(row0 + r) * (KCN * 32) + g * 8;
#pragma unroll
  for (int kc = 0; kc < KCN; ++kc) a[kc] = *(const f16x8*)(ap + kc * 32);
  f16* op = Out + (int64_t)row0 * HP;
#pragma unroll
  for (int ct = 0; ct < 11; ++ct) {
    f32x4 acc = {0.f, 0.f, 0.f, 0.f};
#pragma unroll
    for (int kc = 0; kc < KCN; ++kc) {
      f16x8 b = *(const f16x8*)(Wf + (((size_t)ct * KCN + kc) * 64 + lane) * 8);
      acc = __builtin_amdgcn_mfma_f32_16x16x32_f16(a[kc], b, acc, 0, 0, 0);
    }
    const int col = ct * 16 + r;   // padded col 0..175; pad cols get exact 0
#pragma unroll
    for (int v = 0; v < 4; ++v)
      op[(int64_t)(g * 4 + v) * HP + col] = (f16)acc[v];
  }
}

// ---------------- alpha dot products from padded fp16 h ----------------
__global__ void alpha_kernel(const __half2* __restrict__ H2,
                             const float* __restrict__ asrc,
                             const float* __restrict__ adst,
                             float* __restrict__ as_, float* __restrict__ ad_,
                             int N) {
  int i = blockIdx.x * 256 + threadIdx.x;
  if (i >= N * NH) return;
  int n = i >> 2, h = i & 3;
  const __half2* hp = H2 + (int64_t)n * (HP / 2) + h * (PH / 2);
  const float* ap = asrc + h * CC;
  const float* bp = adst + h * CC;
  float s = 0.f, d = 0.f;
#pragma unroll 7
  for (int j = 0; j < CC / 2; ++j) {
    float2 f = __half22float2(hp[j]);
    s += f.x * ap[2 * j] + f.y * ap[2 * j + 1];
    d += f.x * bp[2 * j] + f.y * bp[2 * j + 1];
  }
  as_[i] = s; ad_[i] = d;
}

// ---------------- counting sort by dst ----------------
__global__ void zero_i_kernel(int* __restrict__ p, int n) {
  int i = blockIdx.x * 256 + threadIdx.x;
  if (i < n) p[i] = 0;
}

__global__ void hist_kernel(const int* __restrict__ dst, int* __restrict__ cnt, int E) {
  int e = blockIdx.x * 256 + threadIdx.x;
  if (e < E) atomicAdd(&cnt[dst[e]], 1);
}

__global__ __launch_bounds__(256) void scan1_kernel(
    const int* __restrict__ cnt, int* __restrict__ rp1, int* __restrict__ blksum, int N) {
  __shared__ int lds[256];
  int t = threadIdx.x;
  int base = blockIdx.x * 1024 + t * 4;
  int v0 = (base + 0 < N) ? cnt[base + 0] : 0;
  int v1 = (base + 1 < N) ? cnt[base + 1] : 0;
  int v2 = (base + 2 < N) ? cnt[base + 2] : 0;
  int v3 = (base + 3 < N) ? cnt[base + 3] : 0;
  v1 += v0; v2 += v1; v3 += v2;
  lds[t] = v3;
  __syncthreads();
  for (int off = 1; off < 256; off <<= 1) {
    int add = (t >= off) ? lds[t - off] : 0;
    __syncthreads();
    lds[t] += add;
    __syncthreads();
  }
  int excl = lds[t] - v3;
  if (base + 0 < N) rp1[base + 0] = excl + v0;
  if (base + 1 < N) rp1[base + 1] = excl + v1;
  if (base + 2 < N) rp1[base + 2] = excl + v2;
  if (base + 3 < N) rp1[base + 3] = excl + v3;
  if (t == 255) blksum[blockIdx.x] = lds[255];
}

__global__ __launch_bounds__(256) void scan2_kernel(int* __restrict__ blksum, int nblk) {
  __shared__ int lds[256];
  int t = threadIdx.x;
  int v = (t < nblk) ? blksum[t] : 0;
  lds[t] = v;
  __syncthreads();
  for (int off = 1; off < 256; off <<= 1) {
    int add = (t >= off) ? lds[t - off] : 0;
    __syncthreads();
    lds[t] += add;
    __syncthreads();
  }
  if (t < nblk) blksum[t] = lds[t] - v;   // exclusive
}

__global__ void scan3_kernel(const int* __restrict__ blksum, int* __restrict__ rp1,
                             int* __restrict__ row_ptr0, int* __restrict__ cnt_cursor, int N) {
  int i = blockIdx.x * 256 + threadIdx.x;
  if (i >= N) return;
  int incl = rp1[i] + blksum[i >> 10];
  rp1[i] = incl;                         // row_ptr[i+1]
  cnt_cursor[i] = incl - cnt_cursor[i];  // row_ptr[i] (exclusive)
  if (i == 0) row_ptr0[0] = 0;
}

__global__ void scatter_kernel(const int* __restrict__ src, const int* __restrict__ dst,
                               int* __restrict__ cursor, int* __restrict__ src_sorted, int E) {
  int e = blockIdx.x * 256 + threadIdx.x;
  if (e >= E) return;
  int pos = atomicAdd(&cursor[dst[e]], 1);
  src_sorted[pos] = src[e];
}

// ---------------- fused GAT aggregation: one wave per dst node ----------------
// Padded-head layout: lane l<44 owns padded channels 4l..4l+3, all in head l/11.
// Per edge: 1 LDS b32 broadcast (pre-scaled byte offset), 1 LDS b32 (head weight),
// one 8B gather, 4 fma + 1 den add. Weights precomputed cooperatively per 64-chunk.
__global__ __launch_bounds__(256) void gat_agg_kernel(
    const int* __restrict__ row_ptr, const int* __restrict__ src_sorted,
    const f16* __restrict__ H16, const float4* __restrict__ as4,
    const float4* __restrict__ ad4_, const float* __restrict__ bias,
    f16* __restrict__ out, int N) {
  __shared__ int   loff[4][64];
  __shared__ float lw4[4][64][4];
  const int wv = threadIdx.x >> 6;
  const int lane = threadIdx.x & 63;
  const int wid = (blockIdx.x * 256 + threadIdx.x) >> 6;
  if (wid >= N) return;               // no barriers; LDS is wave-private
  const int n = wid;
  const bool act = (lane < 44);
  const int hL = act ? (lane / 11) : 0;
  const int myoff = lane * 8;         // byte offset of this lane's 8B within a row
  const float4 adn = ad4_[n];
  float ax = 0.f, ay = 0.f, az = 0.f, aw = 0.f, den = 0.f;

#define GAT_ACC(boff_, w_)                                                  \
  {                                                                         \
    den += w_;                                                              \
    if (act) {                                                              \
      float2 raw = *(const float2*)((const char*)H16 + (boff_) + myoff);    \
      __half2 u0 = *(__half2*)&raw.x, u1 = *(__half2*)&raw.y;               \
      float2 f0 = __half22float2(u0), f1 = __half22float2(u1);              \
      ax += f0.x * w_; ay += f0.y * w_;                                     \
      az += f1.x * w_; aw += f1.y * w_;                                     \
    }                                                                       \
  }

  // self loop
  {
    const float4 a4 = as4[n];
    float4 w4 = make_float4(__expf(lrelu(a4.x + adn.x)), __expf(lrelu(a4.y + adn.y)),
                            __expf(lrelu(a4.z + adn.z)), __expf(lrelu(a4.w + adn.w)));
    float w = sel4(w4, hL);
    GAT_ACC((int64_t)n * HPB, w);
  }

  const int beg = row_ptr[n], end = row_ptr[n + 1];
  for (int base = beg; base < end; base += 64) {
    const int m = min(64, end - base);
    int idx = (lane < m) ? src_sorted[base + lane] : n;
    float4 a4 = as4[idx];
    float4 w4 = make_float4(__expf(lrelu(a4.x + adn.x)), __expf(lrelu(a4.y + adn.y)),
                            __expf(lrelu(a4.z + adn.z)), __expf(lrelu(a4.w + adn.w)));
    loff[wv][lane] = idx * HPB;       // pre-scaled row byte offset
    *(float4*)&lw4[wv][lane][0] = w4;

#define GAT_EDGE(jj)                                                        \
    {                                                                       \
      int boff = loff[wv][jj];                                              \
      float w = lw4[wv][jj][hL];                                            \
      GAT_ACC((int64_t)boff, w);                                            \
    }

    int j = 0;
    for (; j + 8 <= m; j += 8) {
      GAT_EDGE(j)     GAT_EDGE(j + 1) GAT_EDGE(j + 2) GAT_EDGE(j + 3)
      GAT_EDGE(j + 4) GAT_EDGE(j + 5) GAT_EDGE(j + 6) GAT_EDGE(j + 7)
    }
    for (; j < m; ++j) GAT_EDGE(j)
#undef GAT_EDGE
  }
#undef GAT_ACC

  if (lane < 48) {
    f16 o[4] = {(f16)0.f, (f16)0.f, (f16)0.f, (f16)0.f};
    if (act) {
      const int q = lane - hL * 11;           // lane within head
      const float acc[4] = {ax, ay, az, aw};
      const float rden = 1.f / den;
#pragma unroll
      for (int t = 0; t < 4; ++t) {
        int c = q * 4 + t;                    // channel within head (0..43)
        if (c < CC) o[t] = (f16)eluf(acc[t] * rden + bias[hL * CC + c]);
      }
    }
    *(uint2*)(out + (int64_t)n * AP + lane * 4) = *(uint2*)o;  // pads 176..191 zeroed
  }
}

// ---------------- mean pool (batch sorted -> segmented reduce) ----------------
__global__ void gbound_kernel(const int* __restrict__ batch, int* __restrict__ gstart,
                              int N, int G) {
  int i = blockIdx.x * 256 + threadIdx.x;
  if (i > N) return;
  if (i == 0) {
    for (int g = 0; g <= batch[0]; ++g) gstart[g] = 0;
  } else if (i == N) {
    for (int g = batch[N - 1] + 1; g <= G; ++g) gstart[g] = N;
  } else {
    int a = batch[i - 1], b = batch[i];
    for (int g = a + 1; g <= b; ++g) gstart[g] = i;
  }
}

__global__ void zero_f_kernel(float* __restrict__ p, int n) {
  int i = blockIdx.x * 256 + threadIdx.x;
  if (i < n) p[i] = 0.f;
}

#define PSPLIT 4
__global__ __launch_bounds__(192) void pool2_kernel(
    const f16* __restrict__ x, const int* __restrict__ gstart,
    float* __restrict__ sums, int G) {
  int g = blockIdx.x;
  int t = threadIdx.x;
  if (t >= HC) return;
  int pos = (t / CC) * PH + t % CC;   // padded position
  int beg = gstart[g], end = gstart[g + 1];
  float s = 0.f;
  for (int n = beg + (int)blockIdx.y; n < end; n += PSPLIT)
    s += (float)x[(int64_t)n * AP + pos];
  atomicAdd(sums + g * HC + t, s);
}

__global__ void out2_kernel(const float* __restrict__ sums, const int* __restrict__ gstart,
                            float* __restrict__ out, int G) {
  int i = blockIdx.x * 256 + threadIdx.x;
  if (i >= G * HC) return;
  int g = i / HC;
  float cnt = (float)(gstart[g + 1] - gstart[g]);
  out[i] = sums[i] / fmaxf(cnt, 1.f);
}

static inline int cdiv(int64_t a, int b) { return (int)((a + b - 1) / b); }

extern "C" void kernel_launch(void* const* d_in, const int* in_sizes, int n_in,
                              void* d_out, int out_size, void* d_ws, size_t ws_size,
                              hipStream_t stream) {
  const float* x      = (const float*)d_in[0];
  const int*   eidx   = (const int*)d_in[1];
  const int*   batch  = (const int*)d_in[2];
  const float* lin0_w = (const float*)d_in[3];
  const float* lin0_b = (const float*)d_in[4];
  const float* W[3]  = {(const float*)d_in[5],  (const float*)d_in[9],  (const float*)d_in[13]};
  const float* As[3] = {(const float*)d_in[6],  (const float*)d_in[10], (const float*)d_in[14]};
  const float* Ad[3] = {(const float*)d_in[7],  (const float*)d_in[11], (const float*)d_in[15]};
  const float* Bi[3] = {(const float*)d_in[8],  (const float*)d_in[12], (const float*)d_in[16]};

  const int N = in_sizes[2];
  const int E = in_sizes[1] / 2;
  const int G = out_size / HC;
  const int* src = eidx;
  const int* dst = eidx + E;

  // ---- workspace layout ----
  char* p = (char*)d_ws;
  f16* x16  = (f16*)p;  p += (size_t)N * A0P * 2;
  f16* act0 = (f16*)p;  p += (size_t)N * A0P * 2;
  f16* actv = (f16*)p;  p += (size_t)N * AP * 2;
  f16* h16  = (f16*)p;  p += (size_t)N * HP * 2;
  f16* Wf0  = (f16*)p;  p += (size_t)4 * 2 * 64 * 8 * 2;
  f16* Wf1  = (f16*)p;  p += (size_t)11 * 2 * 64 * 8 * 2;
  f16* Wf2  = (f16*)p;  p += (size_t)11 * 6 * 64 * 8 * 2;
  f16* Wf3  = (f16*)p;  p += (size_t)11 * 6 * 64 * 8 * 2;
  float* as_  = (float*)p; p += (size_t)N * NH * 4;
  float* ad_  = (float*)p; p += (size_t)N * NH * 4;
  float* sums = (float*)p; p += (size_t)G * HC * 4;
  int* gstart     = (int*)p; p += (size_t)(G + 1) * 4;
  int* row_ptr    = (int*)p; p += (size_t)(N + 1) * 4;
  int* cursor     = (int*)p; p += (size_t)N * 4;
  int* blksum     = (int*)p; p += 256 * 4;
  int* src_sorted = (int*)p; p += (size_t)E * 4;
  (void)ws_size;

  const int nblk = cdiv(N, 1024);
  const int mfma_blocks = cdiv(cdiv(N, 16), 4);

  // ---- cast + weight tables ----
  cast16_kernel<<<cdiv((int64_t)N * A0P, 256), 256, 0, stream>>>(x, x16, N);
  wconv_kernel<<<cdiv(4 * 2 * 64, 256),  256, 0, stream>>>(lin0_w, Wf0, 4, 2, 0, CC, 0, CC, CC);
  wconv_kernel<<<cdiv(11 * 2 * 64, 256), 256, 0, stream>>>(W[0], Wf1, 11, 2, 0, CC, 1, HC, HC);
  wconv_kernel<<<cdiv(11 * 6 * 64, 256), 256, 0, stream>>>(W[1], Wf2, 11, 6, 1, HC, 1, HC, HC);
  wconv_kernel<<<cdiv(11 * 6 * 64, 256), 256, 0, stream>>>(W[2], Wf3, 11, 6, 1, HC, 1, HC, HC);

  // ---- lin0 + elu -> fp16 act0 ----
  mfma_gemm0_kernel<<<mfma_blocks, 256, 0, stream>>>(x16, Wf0, lin0_b, act0, N);

  // ---- build dst-sorted CSR (once) ----
  zero_i_kernel<<<cdiv(N, 256), 256, 0, stream>>>(cursor, N);
  hist_kernel<<<cdiv(E, 256), 256, 0, stream>>>(dst, cursor, E);
  scan1_kernel<<<nblk, 256, 0, stream>>>(cursor, row_ptr + 1, blksum, N);
  scan2_kernel<<<1, 256, 0, stream>>>(blksum, nblk);
  scan3_kernel<<<cdiv(N, 256), 256, 0, stream>>>(blksum, row_ptr + 1, row_ptr, cursor, N);
  scatter_kernel<<<cdiv(E, 256), 256, 0, stream>>>(src, dst, cursor, src_sorted, E);

  // ---- graph boundaries ----
  gbound_kernel<<<cdiv(N + 1, 256), 256, 0, stream>>>(batch, gstart, N, G);

  // ---- 3 GAT layers ----
  for (int l = 0; l < 3; ++l) {
    if (l == 0)
      mfma_gemmL_kernel<2><<<mfma_blocks, 256, 0, stream>>>(act0, Wf1, h16, N);
    else
      mfma_gemmL_kernel<6><<<mfma_blocks, 256, 0, stream>>>(actv, (l == 1) ? Wf2 : Wf3, h16, N);
    alpha_kernel<<<cdiv((int64_t)N * NH, 256), 256, 0, stream>>>(
        (const __half2*)h16, As[l], Ad[l], as_, ad_, N);
    gat_agg_kernel<<<cdiv(N, 4), 256, 0, stream>>>(
        row_ptr, src_sorted, h16, (const float4*)as_, (const float4*)ad_, Bi[l], actv, N);
  }

  // ---- mean pool per graph ----
  zero_f_kernel<<<cdiv(G * HC, 256), 256, 0, stream>>>(sums, G * HC);
  pool2_kernel<<<dim3(G, PSPLIT), 192, 0, stream>>>(actv, gstart, sums, G);
  out2_kernel<<<cdiv(G * HC, 256), 256, 0, stream>>>(sums, gstart, (float*)d_out, G);
}